// Round 8
// baseline (190.135 us; speedup 1.0000x reference)
//
#include <hip/hip_runtime.h>
#include <hip/hip_bf16.h>
#include <math.h>

// ---------------------------------------------------------------------------
// Round 8: r7 measured ~90% SIMD idle at 1 wave/SIMD (6.2k cyc/tile vs ~600
// issue) -> the lever is TLP, not more ILP. This round halves the per-wave
// register footprint so 2 waves/SIMD fit:
//   - wave PAIR shares each 16-sample tile; each wave owns 64 output features
//     (4 nt) of W2/W3 -> A-frag budget 128 regs (was 256), total ~230.
//     __launch_bounds__(128,2) -> 8 waves/CU.
//   - Y2 halves meet in a DOUBLE-BUFFERED shared LDS tile; exactly 1
//     __syncthreads per tile (write buf tt&1 -> barrier -> read).
//   - both waves build Y1 B-frags in registers (duplicated VALU, no LDS).
//   - per-wave layer-4 partials -> vs[w][816]; elu/ccw/row-reduce ONCE at end
//     (r7's deferred epilogue, kept).
//   - Y1 prefetch dropped (register budget; TLP replaces it).
//   - block 128 = 1 pair = 16 b-rows; grid 1024 exact, no tail.
// Numerics: identical rounding chain to r2-r7 (absmax 0.125 vs thr 0.4725);
// only the fp32 layer-4 sum order changes (split across waves, ~1e-6).
// ---------------------------------------------------------------------------

#define B_N    16384
#define KQ     51
#define HD     128
#define IND    64
#define BLK    128               // 2 waves = 1 pair
#define GRID   1024              // 16384/16 rows
#define RPB    16                // b-rows per block(pair)
#define SPB    (RPB * KQ)        // 816 samples per pair
#define TPB2   (SPB / 16)        // 51 tiles per pair
#define HPITCH 20                // hshT pitch (16B-aligned rows)

typedef __attribute__((ext_vector_type(8))) short short8;
typedef __attribute__((ext_vector_type(4))) float f32x4;

union S8U { short8 s8; unsigned u[4]; };

__device__ __forceinline__ unsigned short f2bf(float f) {
    __hip_bfloat16 t = __float2bfloat16(f);
    return *reinterpret_cast<unsigned short*>(&t);
}

#if defined(__gfx950__) && defined(__has_builtin)
#if __has_builtin(__builtin_amdgcn_cvt_pk_bf16_f32)
#define HAVE_PK_BF16 1
#endif
#endif

__device__ __forceinline__ unsigned pk_bf16(float lo, float hi) {
#ifdef HAVE_PK_BF16
    typedef __attribute__((ext_vector_type(2))) __bf16 bfv2;
    bfv2 r = __builtin_amdgcn_cvt_pk_bf16_f32(lo, hi);
    return *reinterpret_cast<unsigned*>(&r);
#else
    return (unsigned)f2bf(lo) | ((unsigned)f2bf(hi) << 16);
#endif
}

__launch_bounds__(BLK, 2)
__global__ void umnn_fused(const float* __restrict__ x,  const float* __restrict__ h,
                           const float* __restrict__ W1, const float* __restrict__ b1,
                           const float* __restrict__ W2, const float* __restrict__ b2,
                           const float* __restrict__ W3, const float* __restrict__ b3,
                           const float* __restrict__ W4, const float* __restrict__ b4,
                           float* __restrict__ out)
{
    __shared__ __align__(16) float hpL[RPB * HD];       // 8 KB block hpart
    __shared__ __align__(16) char  y2b[2][16 * 256];    // 8 KB Y2 double-buffer
    __shared__ __align__(16) float hshT[63 * HPITCH];   // 5 KB h^T staging
    __shared__ float vs[2][SPB];                        // 6.5 KB wave partials
    __shared__ float xL[RPB];
    __shared__ float sSteps[KQ], sCcw[KQ];
    __shared__ float red2[2];

    const int tid  = threadIdx.x;
    const int w    = tid >> 6;
    const int lane = tid & 63;
    const int q    = lane >> 4;
    const int lm   = lane & 15;
    const int swz  = lm & 7;
    const int rowBase = blockIdx.x * RPB;

    // ---- CC tables (validated r4 formula) ----
    if (tid < KQ) {
        const int j = tid;
        const float pi50 = 0.06283185307179586f;
        sSteps[j] = __cosf((float)j * pi50);
        float s = 0.0f;
        for (int i = 0; i <= 50; i += 2) {
            float Wi = (i == 0) ? 1.0f : 2.0f / (1.0f - (float)(i * i));
            float lam;
            if (j == 0) lam = 0.5f;
            else {
                int mp = (i * j) % 100;
                lam = __cosf((float)mp * pi50);
                if (j == 50) lam *= 0.5f;
            }
            s += (lam * 0.04f) * Wi;
        }
        sCcw[j] = s;
    }
    // ---- xmax scan (x: 64 KB, cache-resident) ----
    {
        const f32x4* x4 = (const f32x4*)x;
        float mx = -1e30f;
        for (int i = tid; i < B_N / 4; i += BLK) {
            f32x4 v = x4[i];
            mx = fmaxf(fmaxf(mx, fmaxf(v[0], v[1])), fmaxf(v[2], v[3]));
        }
        #pragma unroll
        for (int d = 32; d > 0; d >>= 1) mx = fmaxf(mx, __shfl_xor(mx, d));
        if (lane == 0) red2[w] = mx;
    }
    // ---- stage h^T (16 rows); init xL ----
    for (int i = tid; i < RPB * 63; i += BLK) {
        int r = i / 63, d = i - r * 63;
        hshT[d * HPITCH + r] = h[rowBase * 63 + i];
    }
    if (tid < RPB) xL[tid] = x[rowBase + tid];
    __syncthreads();                                   // B1

    const float xmax = fmaxf(red2[0], red2[1]) + 10.0f;

    // ---- block hpart: thread tid = feature n, 16 row-accumulators ----
    {
        const int n = tid;
        float acc[RPB];
        const float b1v = b1[n];
        #pragma unroll
        for (int r = 0; r < RPB; ++r) acc[r] = b1v;
        const float* wr = W1 + n * IND + 1;
        #pragma unroll 1
        for (int d = 0; d < IND - 1; ++d) {
            float wv = wr[d];
            const float* ht = hshT + d * HPITCH;
            #pragma unroll
            for (int rc = 0; rc < RPB / 4; ++rc) {
                f32x4 hv = *(const f32x4*)(ht + rc * 4);
                acc[rc * 4 + 0] = fmaf(wv, hv[0], acc[rc * 4 + 0]);
                acc[rc * 4 + 1] = fmaf(wv, hv[1], acc[rc * 4 + 1]);
                acc[rc * 4 + 2] = fmaf(wv, hv[2], acc[rc * 4 + 2]);
                acc[rc * 4 + 3] = fmaf(wv, hv[3], acc[rc * 4 + 3]);
            }
        }
        #pragma unroll
        for (int r = 0; r < RPB; ++r) hpL[r * HD + n] = acc[r];
    }

    // ---- wave-resident weights/biases: THIS WAVE'S 64 output features ----
    float w1x[32];
    #pragma unroll
    for (int kk = 0; kk < 4; ++kk)
        #pragma unroll
        for (int j = 0; j < 8; ++j)
            w1x[kk * 8 + j] = W1[(kk * 32 + q * 8 + j) * IND];

    short8 W2A[4][4], W3A[4][4];
    f32x4  b2c[4], b3c[4], W4c[4];
    #pragma unroll
    for (int nt = 0; nt < 4; ++nt) {
        const int ntg = w * 4 + nt;                    // global feature tile
        #pragma unroll
        for (int kk = 0; kk < 4; ++kk) {
            const float* p2 = W2 + (ntg * 16 + lm) * HD + kk * 32 + q * 8;
            const float* p3 = W3 + (ntg * 16 + lm) * HD + kk * 32 + q * 8;
            S8U a2, a3;
            #pragma unroll
            for (int j = 0; j < 4; ++j) {
                a2.u[j] = pk_bf16(p2[2 * j], p2[2 * j + 1]);
                a3.u[j] = pk_bf16(p3[2 * j], p3[2 * j + 1]);
            }
            W2A[nt][kk] = a2.s8; W3A[nt][kk] = a3.s8;
        }
        b2c[nt] = *(const f32x4*)(b2 + ntg * 16 + q * 4);
        b3c[nt] = *(const f32x4*)(b3 + ntg * 16 + q * 4);
        W4c[nt] = *(const f32x4*)(W4 + ntg * 16 + q * 4);
    }
    const float b4v = b4[0];
    float* vsW = vs[w];
    __syncthreads();                                   // B2 (hpL ready)

    const int S0 = blockIdx.x * SPB;

    // ================= pair tile loop: 1 barrier per tile =================
    #pragma unroll 1
    for (int tt = 0; tt < TPB2; ++tt) {
        char* buf = y2b[tt & 1];

        // ---- Y1 B-frags in registers (both waves, duplicated) ----
        const int s   = S0 + tt * 16 + lm;
        const unsigned row = (unsigned)s / KQ;
        const int k   = s - (int)row * KQ;
        const int rl  = (int)row - rowBase;
        const float x0 = xL[rl];
        const float X  = fmaf((xmax - x0) * 0.5f, sSteps[k] + 1.0f, x0);
        short8 Y1[4];
        #pragma unroll
        for (int kk = 0; kk < 4; ++kk) {
            const float* hp = hpL + rl * HD + kk * 32 + q * 8;
            f32x4 ha = *(const f32x4*)hp;
            f32x4 hb = *(const f32x4*)(hp + 4);
            S8U u;
            u.u[0] = pk_bf16(fmaxf(fmaf(X, w1x[kk*8+0], ha[0]), 0.f),
                             fmaxf(fmaf(X, w1x[kk*8+1], ha[1]), 0.f));
            u.u[1] = pk_bf16(fmaxf(fmaf(X, w1x[kk*8+2], ha[2]), 0.f),
                             fmaxf(fmaf(X, w1x[kk*8+3], ha[3]), 0.f));
            u.u[2] = pk_bf16(fmaxf(fmaf(X, w1x[kk*8+4], hb[0]), 0.f),
                             fmaxf(fmaf(X, w1x[kk*8+5], hb[1]), 0.f));
            u.u[3] = pk_bf16(fmaxf(fmaf(X, w1x[kk*8+6], hb[2]), 0.f),
                             fmaxf(fmaf(X, w1x[kk*8+7], hb[3]), 0.f));
            Y1[kk] = u.s8;
        }

        // ---- layer 2: 16 MFMA (this wave's 64 features) ----
        f32x4 C[4];
        #pragma unroll
        for (int nt = 0; nt < 4; ++nt) C[nt] = b2c[nt];
        #pragma unroll
        for (int kk = 0; kk < 4; ++kk)
            #pragma unroll
            for (int nt = 0; nt < 4; ++nt)
                C[nt] = __builtin_amdgcn_mfma_f32_16x16x32_bf16(W2A[nt][kk], Y1[kk], C[nt], 0, 0, 0);

        // ---- Y2 half -> shared double-buffer ----
        #pragma unroll
        for (int nt = 0; nt < 4; ++nt) {
            const int cch = 2 * (w * 4 + nt) + (q >> 1);
            unsigned lo = pk_bf16(fmaxf(C[nt][0], 0.f), fmaxf(C[nt][1], 0.f));
            unsigned hi = pk_bf16(fmaxf(C[nt][2], 0.f), fmaxf(C[nt][3], 0.f));
            *(int2*)(buf + lm * 256 + ((cch ^ swz) << 4) + ((q & 1) << 3))
                = make_int2((int)lo, (int)hi);
        }
        __syncthreads();                               // Y2 tile complete

        // ---- layer 3: full-K B-frags from shared Y2 ----
        short8 Y2[4];
        #pragma unroll
        for (int kk = 0; kk < 4; ++kk)
            Y2[kk] = *(const short8*)(buf + lm * 256 + (((kk * 4 + q) ^ swz) << 4));
        #pragma unroll
        for (int nt = 0; nt < 4; ++nt) C[nt] = b3c[nt];
        #pragma unroll
        for (int kk = 0; kk < 4; ++kk)
            #pragma unroll
            for (int nt = 0; nt < 4; ++nt)
                C[nt] = __builtin_amdgcn_mfma_f32_16x16x32_bf16(W3A[nt][kk], Y2[kk], C[nt], 0, 0, 0);

        // ---- layer 4 partial (this wave's 64 features): q-reduce, store ----
        float p = 0.f;
        #pragma unroll
        for (int nt = 0; nt < 4; ++nt) {
            p = fmaf(fmaxf(C[nt][0], 0.f), W4c[nt][0], p);
            p = fmaf(fmaxf(C[nt][1], 0.f), W4c[nt][1], p);
            p = fmaf(fmaxf(C[nt][2], 0.f), W4c[nt][2], p);
            p = fmaf(fmaxf(C[nt][3], 0.f), W4c[nt][3], p);
        }
        p += __shfl_xor(p, 16);
        p += __shfl_xor(p, 32);
        if (lane < 16) vsW[tt * 16 + lm] = p;
    }
    __syncthreads();                                   // vs complete

    // ---- deferred epilogue (wave 0): elu+ccw+row-reduce, plain stores ----
    if (w == 0) {
        const int r   = lane >> 2;          // block row 0..15
        const int sub = lane & 3;
        float a = 0.f;
        #pragma unroll 1
        for (int j = 0; j < 13; ++j) {
            int k = sub + 4 * j;
            if (k < KQ) {
                int sl = r * KQ + k;
                float y4 = vs[0][sl] + vs[1][sl] + b4v;
                float f  = (y4 > 0.f) ? (y4 + 1.f) : __expf(y4);
                a = fmaf(f, sCcw[k], a);
            }
        }
        a += __shfl_xor(a, 1);
        a += __shfl_xor(a, 2);
        if (sub == 0)
            out[rowBase + r] = a * (xmax - xL[r]) * 0.5f;
    }
}

// ---------------------------------------------------------------------------
extern "C" void kernel_launch(void* const* d_in, const int* in_sizes, int n_in,
                              void* d_out, int out_size, void* d_ws, size_t ws_size,
                              hipStream_t stream)
{
    const float* x  = (const float*)d_in[0];
    const float* h  = (const float*)d_in[1];
    const float* W1 = (const float*)d_in[2];
    const float* b1 = (const float*)d_in[3];
    const float* W2 = (const float*)d_in[4];
    const float* b2 = (const float*)d_in[5];
    const float* W3 = (const float*)d_in[6];
    const float* b3 = (const float*)d_in[7];
    const float* W4 = (const float*)d_in[8];
    const float* b4 = (const float*)d_in[9];
    float* out = (float*)d_out;

    umnn_fused<<<GRID, BLK, 0, stream>>>(x, h, W1, b1, W2, b2, W3, b3,
                                         W4, b4, out);
}